// Round 1
// baseline (319.202 us; speedup 1.0000x reference)
//
#include <hip/hip_runtime.h>

#define N_NODES 50000
#define E_EDGES 800000
#define IN_DIM  128
#define OUT_DIM 64
#define NEG_SLOPE 0.01f

// ---- order-preserving float<->uint encoding for atomicMax on floats ----
__device__ __forceinline__ unsigned fenc(float f) {
    unsigned u = __float_as_uint(f);
    return (u & 0x80000000u) ? ~u : (u | 0x80000000u);
}
__device__ __forceinline__ float fdec(unsigned u) {
    return __uint_as_float((u & 0x80000000u) ? (u & 0x7fffffffu) : ~u);
}

// ============================================================
// Kernel 1: z = h @ Wf^T, zr = h @ Wfr^T  (N x 64 each) plus per-node
// attention scalars a4[n] = (dot(z[n],Wa[0:64]), dot(z[n],Wa[64:128]),
//                            dot(zr[n],Wa[0:64]), dot(zr[n],Wa[64:128]))
// block = 256 threads, 64 nodes/block.
// thread: og = tid%16 -> outs og*4..og*4+3 ; ng = tid/16 -> nodes ng*4..+3
// ============================================================
__global__ __launch_bounds__(256) void node_gemm(
    const float* __restrict__ h, const float* __restrict__ Wf,
    const float* __restrict__ Wfr, const float* __restrict__ Wa,
    float* __restrict__ z, float* __restrict__ zr, float4* __restrict__ a4)
{
    __shared__ float hs [64][33];   // pad 33: conflict-free b32 reads
    __shared__ float wfs[64][33];
    __shared__ float wrs[64][33];

    const int tid = threadIdx.x;
    const int og = tid & 15;
    const int ng = tid >> 4;
    const int nb0 = blockIdx.x * 64;

    float accf[4][4] = {{0.f}};
    float accr[4][4] = {{0.f}};

    for (int kb = 0; kb < IN_DIM; kb += 32) {
        __syncthreads();   // protect LDS from previous chunk's readers
        // stage 64 rows x 32 cols of h, Wf, Wfr (float4 global loads)
        const int j = tid & 7;     // float4 index within 32-col row
        const int r0 = tid >> 3;   // 0..31
        for (int rr = r0; rr < 64; rr += 32) {
            int hn = nb0 + rr; if (hn >= N_NODES) hn = N_NODES - 1;
            float4 hv = *(const float4*)&h  [(size_t)hn * IN_DIM + kb + j*4];
            float4 fv = *(const float4*)&Wf [(size_t)rr * IN_DIM + kb + j*4];
            float4 rv = *(const float4*)&Wfr[(size_t)rr * IN_DIM + kb + j*4];
            hs [rr][j*4+0] = hv.x; hs [rr][j*4+1] = hv.y; hs [rr][j*4+2] = hv.z; hs [rr][j*4+3] = hv.w;
            wfs[rr][j*4+0] = fv.x; wfs[rr][j*4+1] = fv.y; wfs[rr][j*4+2] = fv.z; wfs[rr][j*4+3] = fv.w;
            wrs[rr][j*4+0] = rv.x; wrs[rr][j*4+1] = rv.y; wrs[rr][j*4+2] = rv.z; wrs[rr][j*4+3] = rv.w;
        }
        __syncthreads();

        #pragma unroll 8
        for (int k = 0; k < 32; ++k) {
            float hv[4], wfv[4], wrv[4];
            #pragma unroll
            for (int i = 0; i < 4; ++i) hv[i] = hs[ng*4+i][k];
            #pragma unroll
            for (int jj = 0; jj < 4; ++jj) { wfv[jj] = wfs[og*4+jj][k]; wrv[jj] = wrs[og*4+jj][k]; }
            #pragma unroll
            for (int i = 0; i < 4; ++i)
                #pragma unroll
                for (int jj = 0; jj < 4; ++jj) {
                    accf[i][jj] = fmaf(hv[i], wfv[jj], accf[i][jj]);
                    accr[i][jj] = fmaf(hv[i], wrv[jj], accr[i][jj]);
                }
        }
    }

    // epilogue: store z/zr (float4) + wave-group reduce the 4 scalars
    const float4 waS = *(const float4*)&Wa[og*4];
    const float4 waD = *(const float4*)&Wa[64 + og*4];

    #pragma unroll
    for (int i = 0; i < 4; ++i) {
        const int n = nb0 + ng*4 + i;
        const bool valid = (n < N_NODES);
        if (valid) {
            *(float4*)&z [(size_t)n*OUT_DIM + og*4] = make_float4(accf[i][0], accf[i][1], accf[i][2], accf[i][3]);
            *(float4*)&zr[(size_t)n*OUT_DIM + og*4] = make_float4(accr[i][0], accr[i][1], accr[i][2], accr[i][3]);
        }
        float ps = accf[i][0]*waS.x + accf[i][1]*waS.y + accf[i][2]*waS.z + accf[i][3]*waS.w;
        float pd = accf[i][0]*waD.x + accf[i][1]*waD.y + accf[i][2]*waD.z + accf[i][3]*waD.w;
        float qs = accr[i][0]*waS.x + accr[i][1]*waS.y + accr[i][2]*waS.z + accr[i][3]*waS.w;
        float qd = accr[i][0]*waD.x + accr[i][1]*waD.y + accr[i][2]*waD.z + accr[i][3]*waD.w;
        #pragma unroll
        for (int mm = 1; mm < 16; mm <<= 1) {
            ps += __shfl_xor(ps, mm, 64);
            pd += __shfl_xor(pd, mm, 64);
            qs += __shfl_xor(qs, mm, 64);
            qd += __shfl_xor(qd, mm, 64);
        }
        if (og == 0 && valid) a4[n] = make_float4(ps, pd, qs, qd);
    }
}

// ============================================================
// Kernel 2: per-edge logits e_msg + segment-max into menc[dst]
// ============================================================
__global__ __launch_bounds__(256) void edge_logits(
    const int* __restrict__ src, const int* __restrict__ dst,
    const float2* __restrict__ dir, const float4* __restrict__ a4,
    float* __restrict__ emsg, unsigned* __restrict__ menc)
{
    int e = blockIdx.x * 256 + threadIdx.x;
    if (e >= E_EDGES) return;
    int sd = src[e], dd = dst[e];
    float2 d = dir[e];
    float4 as = a4[sd];
    float4 ad = a4[dd];
    float ef = as.x + ad.y; ef = ef > 0.f ? ef : NEG_SLOPE * ef;
    float er = as.z + ad.w; er = er > 0.f ? er : NEG_SLOPE * er;
    float em = d.x * ef + d.y * er;
    emsg[e] = em;
    atomicMax(&menc[dd], fenc(em));
}

// ============================================================
// Kernel 3: w = exp(e_msg - m[dst]); segment-sum into ssum[dst]
// ============================================================
__global__ __launch_bounds__(256) void edge_exp(
    const int* __restrict__ dst, const float* __restrict__ emsg,
    const unsigned* __restrict__ menc, float* __restrict__ wbuf,
    float* __restrict__ ssum)
{
    int e = blockIdx.x * 256 + threadIdx.x;
    if (e >= E_EDGES) return;
    int dd = dst[e];
    float m = fdec(menc[dd]);          // deg>0 nodes always have a finite max
    float w = __expf(emsg[e] - m);
    wbuf[e] = w;
    atomicAdd(&ssum[dd], w);
}

// ============================================================
// Kernel 4: out[dst] += alpha * (d0*z[src] + d1*zr[src])
// one wave per edge; lane = output channel (0..63)
// ============================================================
__global__ __launch_bounds__(256) void edge_aggregate(
    const int* __restrict__ src, const int* __restrict__ dst,
    const float2* __restrict__ dir, const float* __restrict__ z,
    const float* __restrict__ zr, const float* __restrict__ wbuf,
    const float* __restrict__ ssum, float* __restrict__ out)
{
    int gid = blockIdx.x * 256 + threadIdx.x;
    int e = gid >> 6;
    int lane = threadIdx.x & 63;
    if (e >= E_EDGES) return;
    int sd = src[e], dd = dst[e];
    float2 d = dir[e];
    float alpha = wbuf[e] / fmaxf(ssum[dd], 1e-9f);
    float q = 0.f;
    if (d.x != 0.f) q += d.x * z [(size_t)sd*OUT_DIM + lane];
    if (d.y != 0.f) q += d.y * zr[(size_t)sd*OUT_DIM + lane];
    atomicAdd(&out[(size_t)dd*OUT_DIM + lane], alpha * q);
}

extern "C" void kernel_launch(void* const* d_in, const int* in_sizes, int n_in,
                              void* d_out, int out_size, void* d_ws, size_t ws_size,
                              hipStream_t stream) {
    const float*  h   = (const float*) d_in[0];
    const float*  Wf  = (const float*) d_in[1];
    const float*  Wfr = (const float*) d_in[2];
    const float*  Wa  = (const float*) d_in[3];
    const float2* dir = (const float2*)d_in[4];
    const int*    src = (const int*)   d_in[5];
    const int*    dst = (const int*)   d_in[6];
    float* out = (float*)d_out;

    // workspace layout (fp32 words): z[N*64] zr[N*64] a4[N*4] emsg[E] wbuf[E] menc[N] ssum[N]
    float*    z    = (float*)d_ws;
    float*    zr   = z  + (size_t)N_NODES * OUT_DIM;
    float4*   a4   = (float4*)(zr + (size_t)N_NODES * OUT_DIM);
    float*    emsg = (float*)(a4 + N_NODES);
    float*    wbuf = emsg + E_EDGES;
    unsigned* menc = (unsigned*)(wbuf + E_EDGES);
    float*    ssum = (float*)(menc + N_NODES);

    hipMemsetAsync(d_out, 0, (size_t)N_NODES * OUT_DIM * sizeof(float), stream);
    hipMemsetAsync(menc, 0, (size_t)N_NODES * 2 * sizeof(unsigned), stream); // menc + ssum

    node_gemm<<<(N_NODES + 63) / 64, 256, 0, stream>>>(h, Wf, Wfr, Wa, z, zr, a4);
    edge_logits<<<(E_EDGES + 255) / 256, 256, 0, stream>>>(src, dst, dir, a4, emsg, menc);
    edge_exp<<<(E_EDGES + 255) / 256, 256, 0, stream>>>(dst, emsg, menc, wbuf, ssum);
    edge_aggregate<<<(size_t)E_EDGES * 64 / 256, 256, 0, stream>>>(src, dst, dir, z, zr, wbuf, ssum, out);
}

// Round 2
// 200.105 us; speedup vs baseline: 1.5952x; 1.5952x over previous
//
#include <hip/hip_runtime.h>

#define N_NODES 50000
#define E_EDGES 800000
#define IN_DIM  128
#define OUT_DIM 64
#define NEG_SLOPE 0.01f
#define SCAN_NB  ((N_NODES + 255) / 256)   // 196

// ============================================================
// Kernel 1: z = h @ Wf^T, zr = h @ Wfr^T  (N x 64 each) plus per-node
// attention scalars a4[n] = (dot(z,Wa[:64]), dot(z,Wa[64:]),
//                            dot(zr,Wa[:64]), dot(zr,Wa[64:]))
// ============================================================
__global__ __launch_bounds__(256) void node_gemm(
    const float* __restrict__ h, const float* __restrict__ Wf,
    const float* __restrict__ Wfr, const float* __restrict__ Wa,
    float* __restrict__ z, float* __restrict__ zr, float4* __restrict__ a4)
{
    __shared__ float hs [64][33];
    __shared__ float wfs[64][33];
    __shared__ float wrs[64][33];

    const int tid = threadIdx.x;
    const int og = tid & 15;
    const int ng = tid >> 4;
    const int nb0 = blockIdx.x * 64;

    float accf[4][4] = {{0.f}};
    float accr[4][4] = {{0.f}};

    for (int kb = 0; kb < IN_DIM; kb += 32) {
        __syncthreads();
        const int j = tid & 7;
        const int r0 = tid >> 3;
        for (int rr = r0; rr < 64; rr += 32) {
            int hn = nb0 + rr; if (hn >= N_NODES) hn = N_NODES - 1;
            float4 hv = *(const float4*)&h  [(size_t)hn * IN_DIM + kb + j*4];
            float4 fv = *(const float4*)&Wf [(size_t)rr * IN_DIM + kb + j*4];
            float4 rv = *(const float4*)&Wfr[(size_t)rr * IN_DIM + kb + j*4];
            hs [rr][j*4+0] = hv.x; hs [rr][j*4+1] = hv.y; hs [rr][j*4+2] = hv.z; hs [rr][j*4+3] = hv.w;
            wfs[rr][j*4+0] = fv.x; wfs[rr][j*4+1] = fv.y; wfs[rr][j*4+2] = fv.z; wfs[rr][j*4+3] = fv.w;
            wrs[rr][j*4+0] = rv.x; wrs[rr][j*4+1] = rv.y; wrs[rr][j*4+2] = rv.z; wrs[rr][j*4+3] = rv.w;
        }
        __syncthreads();

        #pragma unroll 8
        for (int k = 0; k < 32; ++k) {
            float hv[4], wfv[4], wrv[4];
            #pragma unroll
            for (int i = 0; i < 4; ++i) hv[i] = hs[ng*4+i][k];
            #pragma unroll
            for (int jj = 0; jj < 4; ++jj) { wfv[jj] = wfs[og*4+jj][k]; wrv[jj] = wrs[og*4+jj][k]; }
            #pragma unroll
            for (int i = 0; i < 4; ++i)
                #pragma unroll
                for (int jj = 0; jj < 4; ++jj) {
                    accf[i][jj] = fmaf(hv[i], wfv[jj], accf[i][jj]);
                    accr[i][jj] = fmaf(hv[i], wrv[jj], accr[i][jj]);
                }
        }
    }

    const float4 waS = *(const float4*)&Wa[og*4];
    const float4 waD = *(const float4*)&Wa[64 + og*4];

    #pragma unroll
    for (int i = 0; i < 4; ++i) {
        const int n = nb0 + ng*4 + i;
        const bool valid = (n < N_NODES);
        if (valid) {
            *(float4*)&z [(size_t)n*OUT_DIM + og*4] = make_float4(accf[i][0], accf[i][1], accf[i][2], accf[i][3]);
            *(float4*)&zr[(size_t)n*OUT_DIM + og*4] = make_float4(accr[i][0], accr[i][1], accr[i][2], accr[i][3]);
        }
        float ps = accf[i][0]*waS.x + accf[i][1]*waS.y + accf[i][2]*waS.z + accf[i][3]*waS.w;
        float pd = accf[i][0]*waD.x + accf[i][1]*waD.y + accf[i][2]*waD.z + accf[i][3]*waD.w;
        float qs = accr[i][0]*waS.x + accr[i][1]*waS.y + accr[i][2]*waS.z + accr[i][3]*waS.w;
        float qd = accr[i][0]*waD.x + accr[i][1]*waD.y + accr[i][2]*waD.z + accr[i][3]*waD.w;
        #pragma unroll
        for (int mm = 1; mm < 16; mm <<= 1) {
            ps += __shfl_xor(ps, mm, 64);
            pd += __shfl_xor(pd, mm, 64);
            qs += __shfl_xor(qs, mm, 64);
            qd += __shfl_xor(qd, mm, 64);
        }
        if (og == 0 && valid) a4[n] = make_float4(ps, pd, qs, qd);
    }
}

// ============================================================
// CSR build: histogram -> 2-level exclusive scan -> scatter
// ============================================================
__global__ __launch_bounds__(256) void hist_kernel(
    const int* __restrict__ dst, int* __restrict__ deg)
{
    int e = blockIdx.x * 256 + threadIdx.x;
    if (e < E_EDGES) atomicAdd(&deg[dst[e]], 1);
}

__global__ __launch_bounds__(256) void scan1_kernel(
    const int* __restrict__ deg, int* __restrict__ excl, int* __restrict__ bsum)
{
    __shared__ int tmp[256];
    int tid = threadIdx.x;
    int i = blockIdx.x * 256 + tid;
    int v = (i < N_NODES) ? deg[i] : 0;
    tmp[tid] = v; __syncthreads();
    #pragma unroll
    for (int off = 1; off < 256; off <<= 1) {
        int t = (tid >= off) ? tmp[tid - off] : 0;
        __syncthreads();
        tmp[tid] += t;
        __syncthreads();
    }
    if (i < N_NODES) excl[i] = tmp[tid] - v;
    if (tid == 255) bsum[blockIdx.x] = tmp[tid];
}

__global__ __launch_bounds__(256) void scan2_kernel(
    const int* __restrict__ bsum, int* __restrict__ boff)
{
    __shared__ int tmp[256];
    int tid = threadIdx.x;
    int v = (tid < SCAN_NB) ? bsum[tid] : 0;
    tmp[tid] = v; __syncthreads();
    #pragma unroll
    for (int off = 1; off < 256; off <<= 1) {
        int t = (tid >= off) ? tmp[tid - off] : 0;
        __syncthreads();
        tmp[tid] += t;
        __syncthreads();
    }
    if (tid < SCAN_NB) boff[tid] = tmp[tid] - v;
}

__global__ __launch_bounds__(256) void scan3_kernel(
    int* __restrict__ excl, const int* __restrict__ boff)
{
    int i = blockIdx.x * 256 + threadIdx.x;
    if (i < N_NODES) excl[i] += boff[blockIdx.x];
}

// scatter edges into CSR buckets; pack src index + dirbit into one int
__global__ __launch_bounds__(256) void scatter_kernel(
    const int* __restrict__ src, const int* __restrict__ dst,
    const float2* __restrict__ dir, const int* __restrict__ start,
    int* __restrict__ cursor, int* __restrict__ csr)
{
    int e = blockIdx.x * 256 + threadIdx.x;
    if (e >= E_EDGES) return;
    int dd = dst[e];
    int pos = atomicAdd(&cursor[dd], 1);
    float2 d = dir[e];
    int packed = src[e] | ((d.y != 0.f) ? 0x80000000 : 0);
    csr[start[dd] + pos] = packed;
}

// ============================================================
// Fused per-node softmax + aggregation. One wave per node.
// lane = output channel. Online softmax over CSR edge list.
// ============================================================
__global__ __launch_bounds__(256) void node_aggregate(
    const int* __restrict__ start, const int* __restrict__ deg,
    const int* __restrict__ csr, const float4* __restrict__ a4,
    const float* __restrict__ z, const float* __restrict__ zr,
    float* __restrict__ out)
{
    int gid = blockIdx.x * 256 + threadIdx.x;
    int node = gid >> 6;
    int lane = threadIdx.x & 63;
    if (node >= N_NODES) return;

    const int s0 = start[node];
    const int s1 = s0 + deg[node];
    const float4 an = a4[node];   // need an.y (fwd dst term), an.w (rev dst term)

    float m = -__builtin_inff();
    float ssum = 0.f;
    float acc = 0.f;

    for (int base = s0; base < s1; base += 64) {
        int k = base + lane;
        int p = 0;
        float em = -__builtin_inff();
        if (k < s1) {
            p = csr[k];
            int sd = p & 0x7FFFFFFF;
            float4 a = a4[sd];
            float t = (p < 0) ? (a.z + an.w) : (a.x + an.y);
            em = (t > 0.f) ? t : NEG_SLOPE * t;
        }
        // wave max of em
        float cm = em;
        #pragma unroll
        for (int off = 1; off < 64; off <<= 1) cm = fmaxf(cm, __shfl_xor(cm, off, 64));
        float nm = fmaxf(m, cm);                 // finite: chunk has >=1 edge
        float scale = __expf(m - nm);            // first iter: exp(-inf)=0, s=acc=0
        ssum *= scale; acc *= scale;
        m = nm;
        float w = (k < s1) ? __expf(em - nm) : 0.f;
        float ws = w;
        #pragma unroll
        for (int off = 1; off < 64; off <<= 1) ws += __shfl_xor(ws, off, 64);
        ssum += ws;
        // sequential over this chunk's edges: lane = channel
        int cnt = s1 - base; if (cnt > 64) cnt = 64;
        for (int j = 0; j < cnt; ++j) {
            float wj = __shfl(w, j, 64);
            int   pj = __shfl(p, j, 64);
            int sdj = pj & 0x7FFFFFFF;
            const float* __restrict__ row = (pj < 0) ? zr : z;
            acc = fmaf(wj, row[(size_t)sdj * OUT_DIM + lane], acc);
        }
    }

    out[(size_t)node * OUT_DIM + lane] = acc / fmaxf(ssum, 1e-9f);
}

extern "C" void kernel_launch(void* const* d_in, const int* in_sizes, int n_in,
                              void* d_out, int out_size, void* d_ws, size_t ws_size,
                              hipStream_t stream) {
    const float*  h   = (const float*) d_in[0];
    const float*  Wf  = (const float*) d_in[1];
    const float*  Wfr = (const float*) d_in[2];
    const float*  Wa  = (const float*) d_in[3];
    const float2* dir = (const float2*)d_in[4];
    const int*    src = (const int*)   d_in[5];
    const int*    dst = (const int*)   d_in[6];
    float* out = (float*)d_out;

    // workspace layout (4-byte words):
    // z[N*64] zr[N*64] a4[N*4] deg[N] start[N] cursor[N] bsum[256] boff[256] csr[E]
    float*  z      = (float*)d_ws;
    float*  zr     = z  + (size_t)N_NODES * OUT_DIM;
    float4* a4     = (float4*)(zr + (size_t)N_NODES * OUT_DIM);
    int*    deg    = (int*)(a4 + N_NODES);
    int*    start  = deg + N_NODES;
    int*    cursor = start + N_NODES;
    int*    bsum   = cursor + N_NODES;
    int*    boff   = bsum + 256;
    int*    csr    = boff + 256;

    // zero deg + cursor (contiguous would be nicer; they are adjacent except start)
    hipMemsetAsync(deg, 0, N_NODES * sizeof(int), stream);
    hipMemsetAsync(cursor, 0, N_NODES * sizeof(int), stream);

    const int EB = (E_EDGES + 255) / 256;

    node_gemm     <<<(N_NODES + 63) / 64, 256, 0, stream>>>(h, Wf, Wfr, Wa, z, zr, a4);
    hist_kernel   <<<EB, 256, 0, stream>>>(dst, deg);
    scan1_kernel  <<<SCAN_NB, 256, 0, stream>>>(deg, start, bsum);
    scan2_kernel  <<<1, 256, 0, stream>>>(bsum, boff);
    scan3_kernel  <<<SCAN_NB, 256, 0, stream>>>(start, boff);
    scatter_kernel<<<EB, 256, 0, stream>>>(src, dst, dir, start, cursor, csr);
    node_aggregate<<<(N_NODES * 64 + 255) / 256, 256, 0, stream>>>(start, deg, csr, a4, z, zr, out);
}

// Round 4
// 174.511 us; speedup vs baseline: 1.8291x; 1.1467x over previous
//
#include <hip/hip_runtime.h>

#define N_NODES 50000
#define E_EDGES 800000
#define IN_DIM  128
#define OUT_DIM 64
#define NEG_SLOPE 0.01f
#define SCAN_NB  ((N_NODES + 255) / 256)   // 196
#define LDAP 136                            // padded bf16 row stride (128+8)

typedef __attribute__((ext_vector_type(8))) short bf16x8;
typedef __attribute__((ext_vector_type(4))) float f32x4;

__device__ __forceinline__ ushort f2bf(float x) {   // RNE f32 -> bf16
    unsigned u = __float_as_uint(x);
    return (ushort)((u + 0x7FFFu + ((u >> 16) & 1u)) >> 16);
}
__device__ __forceinline__ float bf2f(ushort u) {
    return __uint_as_float(((unsigned)u) << 16);
}

// ============================================================
// Probe: determine the 16x16x32 bf16 MFMA C/D lane mapping at runtime.
// A[i][0]=1+i, B[0][j]=(1+j)^2 (bf16-exact), D[i][j]=(1+i)(1+j)^2 exact fp32.
// flag[0] = 0 (row=(lane>>4)*4+reg, col=lane&15), 1 (swapped), 4 (neither).
// flag[1] = verify mismatch counter, zeroed here.
// ============================================================
__global__ void probe_kernel(int* flag) {
    int lane = threadIdx.x & 63;
    bf16x8 af = {0,0,0,0,0,0,0,0};
    bf16x8 bf = {0,0,0,0,0,0,0,0};
    if (lane < 16) {
        af[0] = (short)f2bf((float)(1 + lane));
        bf[0] = (short)f2bf((float)((1 + lane) * (1 + lane)));
    }
    f32x4 acc = {0.f, 0.f, 0.f, 0.f};
    acc = __builtin_amdgcn_mfma_f32_16x16x32_bf16(af, bf, acc, 0, 0, 0);
    int lr = lane & 15, lq = lane >> 4;
    bool ok0 = true, ok1 = true;
    #pragma unroll
    for (int r = 0; r < 4; ++r) {
        float e0 = (float)((1 + lq * 4 + r) * (1 + lr) * (1 + lr));
        float e1 = (float)((1 + lr) * (1 + lq * 4 + r) * (1 + lq * 4 + r));
        ok0 = ok0 && (acc[r] == e0);
        ok1 = ok1 && (acc[r] == e1);
    }
    int f = __all(ok0 ? 1 : 0) ? 0 : (__all(ok1 ? 1 : 0) ? 1 : 4);
    if (threadIdx.x == 0) { flag[0] = f; flag[1] = 0; }
}

// ============================================================
// MFMA gemm: z = h@Wf^T, zr = h@Wfr^T stored bf16. Epilogue mapping
// chosen by flag[0]; skips if flag>=2 (VALU fallback will run).
// ============================================================
__global__ __launch_bounds__(256) void node_gemm_mfma(
    const float* __restrict__ h, const float* __restrict__ Wf,
    const float* __restrict__ Wfr, const int* __restrict__ flag,
    ushort* __restrict__ z, ushort* __restrict__ zr)
{
    const int flagv = flag[0];
    if (flagv >= 2) return;

    __shared__ ushort hs [64 * LDAP];
    __shared__ ushort wfs[64 * LDAP];
    __shared__ ushort wrs[64 * LDAP];

    const int t = threadIdx.x;
    const int nb0 = blockIdx.x * 64;

    #pragma unroll
    for (int i = 0; i < 8; ++i) {
        int elem = i * 1024 + t * 4;
        int row = elem >> 7, col = elem & 127;
        int hn = nb0 + row; if (hn >= N_NODES) hn = N_NODES - 1;
        float4 hv = *(const float4*)&h  [(size_t)hn  * IN_DIM + col];
        float4 fv = *(const float4*)&Wf [(size_t)row * IN_DIM + col];
        float4 rv = *(const float4*)&Wfr[(size_t)row * IN_DIM + col];
        ushort4 hu = { f2bf(hv.x), f2bf(hv.y), f2bf(hv.z), f2bf(hv.w) };
        ushort4 fu = { f2bf(fv.x), f2bf(fv.y), f2bf(fv.z), f2bf(fv.w) };
        ushort4 ru = { f2bf(rv.x), f2bf(rv.y), f2bf(rv.z), f2bf(rv.w) };
        *(ushort4*)&hs [row * LDAP + col] = hu;
        *(ushort4*)&wfs[row * LDAP + col] = fu;
        *(ushort4*)&wrs[row * LDAP + col] = ru;
    }
    __syncthreads();

    const int w  = t >> 6;
    const int lane = t & 63;
    const int lr = lane & 15;
    const int lq = lane >> 4;

    f32x4 accf[4], accr[4];
    #pragma unroll
    for (int cb = 0; cb < 4; ++cb) {
        accf[cb] = (f32x4){0.f, 0.f, 0.f, 0.f};
        accr[cb] = (f32x4){0.f, 0.f, 0.f, 0.f};
    }

    #pragma unroll
    for (int kc = 0; kc < 4; ++kc) {
        const int koff = kc * 32 + lq * 8;
        bf16x8 af = *(bf16x8*)&hs[(w * 16 + lr) * LDAP + koff];
        #pragma unroll
        for (int cb = 0; cb < 4; ++cb) {
            bf16x8 bfr = *(bf16x8*)&wfs[(cb * 16 + lr) * LDAP + koff];
            bf16x8 brr = *(bf16x8*)&wrs[(cb * 16 + lr) * LDAP + koff];
            accf[cb] = __builtin_amdgcn_mfma_f32_16x16x32_bf16(af, bfr, accf[cb], 0, 0, 0);
            accr[cb] = __builtin_amdgcn_mfma_f32_16x16x32_bf16(af, brr, accr[cb], 0, 0, 0);
        }
    }

    #pragma unroll
    for (int reg = 0; reg < 4; ++reg) {
        const int aIdx = (flagv == 0) ? (lq * 4 + reg) : lr;
        const int bIdx = (flagv == 0) ? lr : (lq * 4 + reg);
        const int node = nb0 + w * 16 + aIdx;
        if (node < N_NODES) {
            #pragma unroll
            for (int cb = 0; cb < 4; ++cb) {
                z [(size_t)node * OUT_DIM + cb * 16 + bIdx] = f2bf(accf[cb][reg]);
                zr[(size_t)node * OUT_DIM + cb * 16 + bIdx] = f2bf(accr[cb][reg]);
            }
        }
    }
}

// ============================================================
// Verify: spot-check 8192 sampled z/zr entries vs direct fp32 dots.
// Any structural garble -> thousands of mismatches -> flag[1] > 0.
// ============================================================
__global__ __launch_bounds__(256) void verify_kernel(
    const float* __restrict__ h, const float* __restrict__ Wf,
    const float* __restrict__ Wfr, const ushort* __restrict__ z,
    const ushort* __restrict__ zr, int* __restrict__ flag)
{
    if (flag[0] >= 2) return;   // mfma skipped; fallback triggers on flag[0]
    int i = blockIdx.x * 256 + threadIdx.x;
    unsigned u = (unsigned)i * 2654435761u;
    int n = (int)(u % (unsigned)N_NODES);
    int o = (int)((u >> 17) & 63);
    const ushort* zz = (i & 1) ? zr : z;
    const float*  W  = (i & 1) ? Wfr : Wf;
    float s = 0.f;
    #pragma unroll 4
    for (int k = 0; k < IN_DIM; k += 4) {
        float4 hv = *(const float4*)&h[(size_t)n * IN_DIM + k];
        float4 wv = *(const float4*)&W[(size_t)o * IN_DIM + k];
        s = fmaf(hv.x, wv.x, s); s = fmaf(hv.y, wv.y, s);
        s = fmaf(hv.z, wv.z, s); s = fmaf(hv.w, wv.w, s);
    }
    float zv = bf2f(zz[(size_t)n * OUT_DIM + o]);
    if (fabsf(s - zv) > 0.125f + 0.02f * fabsf(s)) atomicAdd(&flag[1], 1);
}

// ============================================================
// VALU fallback gemm (round-2 proven), bf16 stores, no a4.
// Runs only if probe failed or verify found mismatches.
// ============================================================
__global__ __launch_bounds__(256) void node_gemm_valu(
    const float* __restrict__ h, const float* __restrict__ Wf,
    const float* __restrict__ Wfr, const int* __restrict__ flag,
    ushort* __restrict__ z, ushort* __restrict__ zr)
{
    if (flag[0] < 2 && flag[1] == 0) return;

    __shared__ float hs [64][33];
    __shared__ float wfs[64][33];
    __shared__ float wrs[64][33];

    const int tid = threadIdx.x;
    const int og = tid & 15;
    const int ng = tid >> 4;
    const int nb0 = blockIdx.x * 64;

    float accf[4][4] = {{0.f}};
    float accr[4][4] = {{0.f}};

    for (int kb = 0; kb < IN_DIM; kb += 32) {
        __syncthreads();
        const int j = tid & 7;
        const int r0 = tid >> 3;
        for (int rr = r0; rr < 64; rr += 32) {
            int hn = nb0 + rr; if (hn >= N_NODES) hn = N_NODES - 1;
            float4 hv = *(const float4*)&h  [(size_t)hn * IN_DIM + kb + j*4];
            float4 fv = *(const float4*)&Wf [(size_t)rr * IN_DIM + kb + j*4];
            float4 rv = *(const float4*)&Wfr[(size_t)rr * IN_DIM + kb + j*4];
            hs [rr][j*4+0] = hv.x; hs [rr][j*4+1] = hv.y; hs [rr][j*4+2] = hv.z; hs [rr][j*4+3] = hv.w;
            wfs[rr][j*4+0] = fv.x; wfs[rr][j*4+1] = fv.y; wfs[rr][j*4+2] = fv.z; wfs[rr][j*4+3] = fv.w;
            wrs[rr][j*4+0] = rv.x; wrs[rr][j*4+1] = rv.y; wrs[rr][j*4+2] = rv.z; wrs[rr][j*4+3] = rv.w;
        }
        __syncthreads();

        #pragma unroll 8
        for (int k = 0; k < 32; ++k) {
            float hv[4], wfv[4], wrv[4];
            #pragma unroll
            for (int i = 0; i < 4; ++i) hv[i] = hs[ng*4+i][k];
            #pragma unroll
            for (int jj = 0; jj < 4; ++jj) { wfv[jj] = wfs[og*4+jj][k]; wrv[jj] = wrs[og*4+jj][k]; }
            #pragma unroll
            for (int i = 0; i < 4; ++i)
                #pragma unroll
                for (int jj = 0; jj < 4; ++jj) {
                    accf[i][jj] = fmaf(hv[i], wfv[jj], accf[i][jj]);
                    accr[i][jj] = fmaf(hv[i], wrv[jj], accr[i][jj]);
                }
        }
    }

    #pragma unroll
    for (int i = 0; i < 4; ++i) {
        const int n = nb0 + ng*4 + i;
        if (n < N_NODES) {
            #pragma unroll
            for (int jj = 0; jj < 4; ++jj) {
                z [(size_t)n*OUT_DIM + og*4 + jj] = f2bf(accf[i][jj]);
                zr[(size_t)n*OUT_DIM + og*4 + jj] = f2bf(accr[i][jj]);
            }
        }
    }
}

// ============================================================
// a4[n] = (dot(z[n],Wa[:64]), dot(z[n],Wa[64:]), dot(zr,Wa[:64]), dot(zr,Wa[64:]))
// 16 lanes per node; layout-independent (reads z/zr from global).
// ============================================================
__global__ __launch_bounds__(256) void a4_kernel(
    const ushort* __restrict__ z, const ushort* __restrict__ zr,
    const float* __restrict__ Wa, float4* __restrict__ a4)
{
    int gid = blockIdx.x * 256 + threadIdx.x;
    int node = gid >> 4;
    int lr = threadIdx.x & 15;
    if (node >= N_NODES) return;
    ushort4 zv = *(const ushort4*)&z [(size_t)node * OUT_DIM + lr * 4];
    ushort4 rv = *(const ushort4*)&zr[(size_t)node * OUT_DIM + lr * 4];
    float4 ws4 = *(const float4*)&Wa[lr * 4];
    float4 wd4 = *(const float4*)&Wa[64 + lr * 4];
    float pSf = bf2f(zv.x)*ws4.x + bf2f(zv.y)*ws4.y + bf2f(zv.z)*ws4.z + bf2f(zv.w)*ws4.w;
    float pDf = bf2f(zv.x)*wd4.x + bf2f(zv.y)*wd4.y + bf2f(zv.z)*wd4.z + bf2f(zv.w)*wd4.w;
    float pSr = bf2f(rv.x)*ws4.x + bf2f(rv.y)*ws4.y + bf2f(rv.z)*ws4.z + bf2f(rv.w)*ws4.w;
    float pDr = bf2f(rv.x)*wd4.x + bf2f(rv.y)*wd4.y + bf2f(rv.z)*wd4.z + bf2f(rv.w)*wd4.w;
    #pragma unroll
    for (int mm = 1; mm < 16; mm <<= 1) {
        pSf += __shfl_xor(pSf, mm, 64);
        pDf += __shfl_xor(pDf, mm, 64);
        pSr += __shfl_xor(pSr, mm, 64);
        pDr += __shfl_xor(pDr, mm, 64);
    }
    if (lr == 0) a4[node] = make_float4(pSf, pDf, pSr, pDr);
}

// ============================================================
// CSR build: histogram -> 2-level exclusive scan -> scatter
// ============================================================
__global__ __launch_bounds__(256) void hist_kernel(
    const int* __restrict__ dst, int* __restrict__ deg)
{
    int e = blockIdx.x * 256 + threadIdx.x;
    if (e < E_EDGES) atomicAdd(&deg[dst[e]], 1);
}

__global__ __launch_bounds__(256) void scan1_kernel(
    const int* __restrict__ deg, int* __restrict__ excl, int* __restrict__ bsum)
{
    __shared__ int tmp[256];
    int tid = threadIdx.x;
    int i = blockIdx.x * 256 + tid;
    int v = (i < N_NODES) ? deg[i] : 0;
    tmp[tid] = v; __syncthreads();
    #pragma unroll
    for (int off = 1; off < 256; off <<= 1) {
        int t = (tid >= off) ? tmp[tid - off] : 0;
        __syncthreads();
        tmp[tid] += t;
        __syncthreads();
    }
    if (i < N_NODES) excl[i] = tmp[tid] - v;
    if (tid == 255) bsum[blockIdx.x] = tmp[tid];
}

__global__ __launch_bounds__(256) void scan2_kernel(
    const int* __restrict__ bsum, int* __restrict__ boff)
{
    __shared__ int tmp[256];
    int tid = threadIdx.x;
    int v = (tid < SCAN_NB) ? bsum[tid] : 0;
    tmp[tid] = v; __syncthreads();
    #pragma unroll
    for (int off = 1; off < 256; off <<= 1) {
        int t = (tid >= off) ? tmp[tid - off] : 0;
        __syncthreads();
        tmp[tid] += t;
        __syncthreads();
    }
    if (tid < SCAN_NB) boff[tid] = tmp[tid] - v;
}

__global__ __launch_bounds__(256) void scan3_kernel(
    int* __restrict__ excl, const int* __restrict__ boff)
{
    int i = blockIdx.x * 256 + threadIdx.x;
    if (i < N_NODES) excl[i] += boff[blockIdx.x];
}

__global__ __launch_bounds__(256) void scatter_kernel(
    const int* __restrict__ src, const int* __restrict__ dst,
    const float2* __restrict__ dir, const int* __restrict__ start,
    int* __restrict__ cursor, int* __restrict__ csr)
{
    int e = blockIdx.x * 256 + threadIdx.x;
    if (e >= E_EDGES) return;
    int dd = dst[e];
    int pos = atomicAdd(&cursor[dd], 1);
    float2 d = dir[e];
    int packed = src[e] | ((d.y != 0.f) ? 0x80000000 : 0);
    csr[start[dd] + pos] = packed;
}

// ============================================================
// Fused per-node softmax + aggregation. One wave per node;
// lane = output channel; z/zr gathered as bf16 (128 B/row).
// ============================================================
__global__ __launch_bounds__(256) void node_aggregate(
    const int* __restrict__ start, const int* __restrict__ deg,
    const int* __restrict__ csr, const float4* __restrict__ a4,
    const ushort* __restrict__ z, const ushort* __restrict__ zr,
    float* __restrict__ out)
{
    int gid = blockIdx.x * 256 + threadIdx.x;
    int node = gid >> 6;
    int lane = threadIdx.x & 63;
    if (node >= N_NODES) return;

    const int s0 = start[node];
    const int s1 = s0 + deg[node];
    const float4 an = a4[node];

    float m = -__builtin_inff();
    float ssum = 0.f;
    float acc = 0.f;

    for (int base = s0; base < s1; base += 64) {
        int k = base + lane;
        int p = 0;
        float em = -__builtin_inff();
        if (k < s1) {
            p = csr[k];
            int sd = p & 0x7FFFFFFF;
            float4 a = a4[sd];
            float tl = (p < 0) ? (a.z + an.w) : (a.x + an.y);
            em = (tl > 0.f) ? tl : NEG_SLOPE * tl;
        }
        float cm = em;
        #pragma unroll
        for (int off = 1; off < 64; off <<= 1) cm = fmaxf(cm, __shfl_xor(cm, off, 64));
        float nm = fmaxf(m, cm);
        float scale = __expf(m - nm);
        ssum *= scale; acc *= scale;
        m = nm;
        float wv = (k < s1) ? __expf(em - nm) : 0.f;
        float ws = wv;
        #pragma unroll
        for (int off = 1; off < 64; off <<= 1) ws += __shfl_xor(ws, off, 64);
        ssum += ws;

        int cnt = s1 - base; if (cnt > 64) cnt = 64;
        int j = 0;
        for (; j + 1 < cnt; j += 2) {
            float w0 = __shfl(wv, j, 64),     w1 = __shfl(wv, j + 1, 64);
            int   p0 = __shfl(p, j, 64),      p1 = __shfl(p, j + 1, 64);
            int sd0 = p0 & 0x7FFFFFFF,        sd1 = p1 & 0x7FFFFFFF;
            const ushort* __restrict__ r0 = (p0 < 0) ? zr : z;
            const ushort* __restrict__ r1 = (p1 < 0) ? zr : z;
            float v0 = bf2f(r0[(size_t)sd0 * OUT_DIM + lane]);
            float v1 = bf2f(r1[(size_t)sd1 * OUT_DIM + lane]);
            acc = fmaf(w0, v0, acc);
            acc = fmaf(w1, v1, acc);
        }
        if (j < cnt) {
            float w0 = __shfl(wv, j, 64);
            int   p0 = __shfl(p, j, 64);
            int sd0 = p0 & 0x7FFFFFFF;
            const ushort* __restrict__ r0 = (p0 < 0) ? zr : z;
            acc = fmaf(w0, bf2f(r0[(size_t)sd0 * OUT_DIM + lane]), acc);
        }
    }

    out[(size_t)node * OUT_DIM + lane] = acc / fmaxf(ssum, 1e-9f);
}

extern "C" void kernel_launch(void* const* d_in, const int* in_sizes, int n_in,
                              void* d_out, int out_size, void* d_ws, size_t ws_size,
                              hipStream_t stream) {
    const float*  h   = (const float*) d_in[0];
    const float*  Wf  = (const float*) d_in[1];
    const float*  Wfr = (const float*) d_in[2];
    const float*  Wa  = (const float*) d_in[3];
    const float2* dir = (const float2*)d_in[4];
    const int*    src = (const int*)   d_in[5];
    const int*    dst = (const int*)   d_in[6];
    float* out = (float*)d_out;

    // ws layout (4B words): z[N*64 bf16] zr[N*64 bf16] a4[N float4] deg[N]
    // start[N] cursor[N] bsum[256] boff[256] flag[64] csr[E]
    ushort* zb     = (ushort*)d_ws;
    ushort* zrb    = zb + (size_t)N_NODES * OUT_DIM;
    float4* a4     = (float4*)(zrb + (size_t)N_NODES * OUT_DIM);
    int*    deg    = (int*)(a4 + N_NODES);
    int*    start  = deg + N_NODES;
    int*    cursor = start + N_NODES;
    int*    bsum   = cursor + N_NODES;
    int*    boff   = bsum + 256;
    int*    flag   = boff + 256;
    int*    csr    = flag + 64;

    hipMemsetAsync(deg, 0, N_NODES * sizeof(int), stream);
    hipMemsetAsync(cursor, 0, N_NODES * sizeof(int), stream);

    const int EB = (E_EDGES + 255) / 256;
    const int GB = (N_NODES + 63) / 64;

    probe_kernel   <<<1, 64, 0, stream>>>(flag);
    node_gemm_mfma <<<GB, 256, 0, stream>>>(h, Wf, Wfr, flag, zb, zrb);
    verify_kernel  <<<32, 256, 0, stream>>>(h, Wf, Wfr, zb, zrb, flag);
    node_gemm_valu <<<GB, 256, 0, stream>>>(h, Wf, Wfr, flag, zb, zrb);
    a4_kernel      <<<(N_NODES * 16 + 255) / 256, 256, 0, stream>>>(zb, zrb, Wa, a4);
    hist_kernel    <<<EB, 256, 0, stream>>>(dst, deg);
    scan1_kernel   <<<SCAN_NB, 256, 0, stream>>>(deg, start, bsum);
    scan2_kernel   <<<1, 256, 0, stream>>>(bsum, boff);
    scan3_kernel   <<<SCAN_NB, 256, 0, stream>>>(start, boff);
    scatter_kernel <<<EB, 256, 0, stream>>>(src, dst, dir, start, cursor, csr);
    node_aggregate <<<(N_NODES * 64 + 255) / 256, 256, 0, stream>>>(start, deg, csr, a4, zb, zrb, out);
}